// Round 10
// baseline (79.100 us; speedup 1.0000x reference)
//
#include <hip/hip_runtime.h>

// Problem constants (match reference)
#define HWPX (512*512)      // pixels per batch
#define NB 2                // batches
#define NL 512              // EH*EW light directions (table rows)
#define NLS 480             // shadeable lights: phi=0 row (32 dirs) has coeff sin(0)=0
#define QNLS 120            // lights per wave-group (4 groups)
#define PXPT 4              // pixels per thread
constexpr float PI_F = 3.14159265358979323846f;
constexpr float INV_SQRT2 = 0.70710678118654752f;

// ws layout (bytes):
//   [0]      unsigned max-bits slot (f32 >= 0, bit-monotone)
//   [256]    float2 tab[2][480][3] : COMPACT per light (phi>=1 rows only):
//            {hx,hy} {hz,e0c} {e1c,e2c}   (c = sin(phi)/60 folded into env)
//
// Identities:
//  * (relu(s)/max)^64 == relu(s)^64 * (1/max)^64, |s|<=1 -> accumulate
//    UNNORMALIZED, track global max in-pass, finalize scales by (1/max)^64.
//  * phi=0 row: coeff==0 -> only matters for the max; h=(0,r2,r2) ->
//    s=(ny+nz)*r2 seeded analytically.
// R7/R8 lessons: v_pk_f32 does not halve VALU cycles (SIMD-32), and the f2
// ext-vector idiom costs ~+3.7 VALU ops/pair in packing overhead. This round:
// fully SCALAR inner loop (floor ~14 ops/pair) + 4-way light split (one wave
// per 120-light group) -> 2048 blocks, 32 waves/CU. Merge buffer aliases the
// dead light table in LDS.

__global__ void k_setup(const float* __restrict__ env,
                        float2* __restrict__ tab,
                        unsigned* __restrict__ maxslot) {
    int m = threadIdx.x;            // 512 threads, one per light dir
    if (m == 0) *maxslot = 0u;      // re-zeroed every launch (replay-safe)
    int p = m >> 5;                 // phi index (EH=16)
    int t = m & 31;                 // theta index (EW=32)
    if (p < 1) return;              // phi=0: zero coeff, handled analytically
    float phi = (float)p * (PI_F / 16.0f);
    float th  = (float)t * (2.0f * PI_F / 32.0f);
    float sp = sinf(phi), cp = cosf(phi);
    float st = sinf(th),  ct = cosf(th);
    // l = (st*sp, cp, -ct*sp); h = l + view(0,0,1), normalized
    float hx = st * sp;
    float hy = cp;
    float hz = 1.0f - ct * sp;
    float inv = rsqrtf(hx * hx + hy * hy + hz * hz);
    hx *= inv; hy *= inv; hz *= inv;
    float c = sp * (1.0f / 60.0f);  // solid-angle coeff and the /60 folded in
    int ms = m - 32;                // shadeable index 0..479
    #pragma unroll
    for (int b = 0; b < NB; ++b) {
        const float* e = env + ((size_t)(b * NL + m)) * 3;
        float2* dst = tab + (size_t)(b * NLS + ms) * 3;
        float2 q0; q0.x = hx;       q0.y = hy;
        float2 q1; q1.x = hz;       q1.y = e[0] * c;
        float2 q2; q2.x = e[1] * c; q2.y = e[2] * c;
        dst[0] = q0; dst[1] = q1; dst[2] = q2;
    }
}

__device__ __forceinline__ void load_normal(const float* __restrict__ normal, size_t pix,
                                            float& nx, float& ny, float& nz) {
    const float* p = normal + pix * 3;
    float c0 = p[0], c1 = p[1], c2 = p[2];
    // channel-reversed, [0,1] -> [-1,1], L2 normalize
    float x = (c2 - 0.5f) * 2.0f;
    float y = (c1 - 0.5f) * 2.0f;
    float z = (c0 - 0.5f) * 2.0f;
    float d2 = x * x + y * y + z * z;
    float inv = d2 > 0.0f ? rsqrtf(d2) : 0.0f;
    nx = x * inv; ny = y * inv; nz = z * inv;
}

// 256 threads = 4 waves; wave g handles lights [g*120,(g+1)*120) for the SAME
// 64x4 pixels. 2048 blocks -> 8 blocks/CU -> 32 waves/CU (HW max).
__global__ __launch_bounds__(256) void k_fused(const float* __restrict__ normal,
                                               const float2* __restrict__ tab,
                                               float* __restrict__ out,
                                               unsigned* __restrict__ maxslot) {
    __shared__ float smem[NLS * 3 * 2];            // 11.25KB table; merge aliases it
    __shared__ float swmax[4];                     // per-wave partial max

    int tid = threadIdx.x;
    int bid = blockIdx.x;
    int bpb = HWPX / 256;                          // 1024 blocks per batch
    int b = bid / bpb;
    int g = tid >> 6;                              // wave-group = light quarter
    int li = tid & 63;                             // pixel lane
    int base_in_b = (bid % bpb) * 256 + li;

    // stage light table: 720 float4s, coalesced
    {
        const float4* gp = reinterpret_cast<const float4*>(tab + (size_t)b * NLS * 3);
        float4* sp4 = reinterpret_cast<float4*>(smem);
        sp4[tid]       = gp[tid];
        sp4[tid + 256] = gp[tid + 256];
        if (tid < 208) sp4[tid + 512] = gp[tid + 512];
    }

    float nx[PXPT], ny[PXPT], nz[PXPT];
    #pragma unroll
    for (int k = 0; k < PXPT; ++k)
        load_normal(normal, (size_t)b * HWPX + base_in_b + k * 64,
                    nx[k], ny[k], nz[k]);

    // phi=0 light max seed (group 0 only): h=(0,r2,r2) -> s=(ny+nz)*r2
    float mx = 0.0f;
    if (g == 0) {
        #pragma unroll
        for (int k = 0; k < PXPT; ++k)
            mx = fmaxf(mx, (ny[k] + nz[k]) * INV_SQRT2);
    }

    __syncthreads();

    float a0[PXPT], a1[PXPT], a2[PXPT];
    #pragma unroll
    for (int k = 0; k < PXPT; ++k) { a0[k] = 0.0f; a1[k] = 0.0f; a2[k] = 0.0f; }

    const float2* Tg = reinterpret_cast<const float2*>(smem) + g * (QNLS * 3);
    #pragma unroll 8
    for (int mm = 0; mm < QNLS; ++mm) {
        float2 q0 = Tg[mm * 3 + 0];                // {hx,hy}  (wave-uniform addr)
        float2 q1 = Tg[mm * 3 + 1];                // {hz,e0}
        float2 q2 = Tg[mm * 3 + 2];                // {e1,e2}
        float hx = q0.x, hy = q0.y, hz = q1.x;
        float e0 = q1.y, e1 = q2.x, e2 = q2.y;

        float rr[PXPT];
        #pragma unroll
        for (int k = 0; k < PXPT; ++k) {
            float s = fmaf(nx[k], hx, fmaf(ny[k], hy, nz[k] * hz));
            float r = fmaxf(s, 0.0f);              // relu
            rr[k] = r;
            float r2  = r * r;
            float r4  = r2 * r2;
            float r8  = r4 * r4;
            float r16 = r8 * r8;
            float r32 = r16 * r16;
            float r64 = r32 * r32;
            a0[k] = fmaf(r64, e0, a0[k]);
            a1[k] = fmaf(r64, e1, a1[k]);
            a2[k] = fmaf(r64, e2, a2[k]);
        }
        mx = fmaxf(mx, fmaxf(fmaxf(rr[0], rr[1]), fmaxf(rr[2], rr[3])));
    }

    // wave-64 max reduce
    #pragma unroll
    for (int off = 32; off > 0; off >>= 1)
        mx = fmaxf(mx, __shfl_xor(mx, off));
    if (li == 0) swmax[g] = mx;

    __syncthreads();   // all table reads done; smem now reusable as merge buffer

    // groups 1..3 deposit partials: stride 13 dwords (odd -> conflict-free)
    if (g > 0) {
        float* dst = smem + (size_t)(g - 1) * (64 * 13) + li * 13;
        #pragma unroll
        for (int k = 0; k < PXPT; ++k) {
            dst[k]     = a0[k];
            dst[k + 4] = a1[k];
            dst[k + 8] = a2[k];
        }
    }
    __syncthreads();

    if (tid == 0) {
        float bm = fmaxf(fmaxf(swmax[0], swmax[1]), fmaxf(swmax[2], swmax[3]));
        atomicMax(maxslot, __float_as_uint(bm));   // f32 >= 0: bit-monotone
    }

    if (g == 0) {
        #pragma unroll
        for (int gg = 0; gg < 3; ++gg) {
            const float* src = smem + (size_t)gg * (64 * 13) + li * 13;
            #pragma unroll
            for (int k = 0; k < PXPT; ++k) {
                a0[k] += src[k];
                a1[k] += src[k + 4];
                a2[k] += src[k + 8];
            }
        }
        // unnormalized sums to out[b][c][h][w]; finalize scales by (1/max)^64
        float* ob = out + (size_t)b * 3 * HWPX;
        #pragma unroll
        for (int k = 0; k < PXPT; ++k) {
            int p = base_in_b + k * 64;
            ob[0 * HWPX + p] = a0[k];
            ob[1 * HWPX + p] = a1[k];
            ob[2 * HWPX + p] = a2[k];
        }
    }
}

__global__ __launch_bounds__(256) void k_finalize(float* __restrict__ out,
                                                  const unsigned* __restrict__ maxslot) {
    float im  = 1.0f / __uint_as_float(*maxslot);   // uniform scalar load
    float i2  = im * im;
    float i4  = i2 * i2;
    float i8  = i4 * i4;
    float i16 = i8 * i8;
    float i32 = i16 * i16;
    float scl = i32 * i32;                          // (1/max)^64
    int i = blockIdx.x * 256 + (int)threadIdx.x;    // over float4s
    float4* o = reinterpret_cast<float4*>(out);
    float4 v = o[i];
    v.x *= scl; v.y *= scl; v.z *= scl; v.w *= scl;
    o[i] = v;
}

extern "C" void kernel_launch(void* const* d_in, const int* in_sizes, int n_in,
                              void* d_out, int out_size, void* d_ws, size_t ws_size,
                              hipStream_t stream) {
    const float* env    = (const float*)d_in[0];   // (B,16,32,3) f32
    const float* normal = (const float*)d_in[1];   // (B,512,512,3) f32
    float* out = (float*)d_out;                    // (B,3,512,512) f32

    char* ws = (char*)d_ws;
    unsigned* maxslot = (unsigned*)ws;
    float2* tab = (float2*)(ws + 256);

    int nblocks = (NB * HWPX) / 256;               // 2048
    int fblocks = (NB * 3 * HWPX) / (4 * 256);     // 1536 (float4 granularity)

    hipLaunchKernelGGL(k_setup, dim3(1), dim3(NL), 0, stream, env, tab, maxslot);
    hipLaunchKernelGGL(k_fused, dim3(nblocks), dim3(256), 0, stream, normal, tab, out, maxslot);
    hipLaunchKernelGGL(k_finalize, dim3(fblocks), dim3(256), 0, stream, out, maxslot);
}

// Round 11
// 75.675 us; speedup vs baseline: 1.0453x; 1.0453x over previous
//
#include <hip/hip_runtime.h>

// Problem constants (match reference)
#define HWPX (512*512)      // pixels per batch
#define NB 2                // batches
#define NL 512              // EH*EW light directions (table rows)
#define NLS 480             // shadeable lights: phi=0 row (32 dirs) has coeff sin(0)=0
#define QNLS 120            // lights per wave-group (4 groups)
#define PXPT 4              // pixels per thread (2 f2 pairs)
constexpr float PI_F = 3.14159265358979323846f;
constexpr float INV_SQRT2 = 0.70710678118654752f;

typedef float f2 __attribute__((ext_vector_type(2)));

// ws layout (bytes):
//   [0]      unsigned max-bits slot (f32 >= 0, bit-monotone)
//   [256]    float2 tab[2][480][3] : COMPACT per light (phi>=1 rows only):
//            {hx,hy} {hz,e0c} {e1c,e2c}   (c = sin(phi)/60 folded into env)
//
// Identities:
//  * (relu(s)/max)^64 == relu(s)^64 * (1/max)^64, |s|<=1 -> accumulate
//    UNNORMALIZED, track global max in-pass, finalize scales by (1/max)^64.
//  * phi=0 row: coeff==0 -> only matters for the max; h=(0,r2,r2) ->
//    s=(ny+nz)*r2 seeded analytically.
//
// R9 lesson: scalar inner loop has HIGHER busy-time (64.6us) than the f2
// packed form (55us) — VALU pipe time is equal (SIMD-32), but f2 halves
// instruction issue slots, and at 32 waves/CU the issue port is the
// contended resource. This round: R9's occupancy structure (4-way light
// split, 2048 blocks) + R8's f2 inner body (lowest busy).

__global__ void k_setup(const float* __restrict__ env,
                        float2* __restrict__ tab,
                        unsigned* __restrict__ maxslot) {
    int m = threadIdx.x;            // 512 threads, one per light dir
    if (m == 0) *maxslot = 0u;      // re-zeroed every launch (replay-safe)
    int p = m >> 5;                 // phi index (EH=16)
    int t = m & 31;                 // theta index (EW=32)
    if (p < 1) return;              // phi=0: zero coeff, handled analytically
    float phi = (float)p * (PI_F / 16.0f);
    float th  = (float)t * (2.0f * PI_F / 32.0f);
    float sp = sinf(phi), cp = cosf(phi);
    float st = sinf(th),  ct = cosf(th);
    // l = (st*sp, cp, -ct*sp); h = l + view(0,0,1), normalized
    float hx = st * sp;
    float hy = cp;
    float hz = 1.0f - ct * sp;
    float inv = rsqrtf(hx * hx + hy * hy + hz * hz);
    hx *= inv; hy *= inv; hz *= inv;
    float c = sp * (1.0f / 60.0f);  // solid-angle coeff and the /60 folded in
    int ms = m - 32;                // shadeable index 0..479
    #pragma unroll
    for (int b = 0; b < NB; ++b) {
        const float* e = env + ((size_t)(b * NL + m)) * 3;
        float2* dst = tab + (size_t)(b * NLS + ms) * 3;
        float2 q0; q0.x = hx;       q0.y = hy;
        float2 q1; q1.x = hz;       q1.y = e[0] * c;
        float2 q2; q2.x = e[1] * c; q2.y = e[2] * c;
        dst[0] = q0; dst[1] = q1; dst[2] = q2;
    }
}

__device__ __forceinline__ void load_normal(const float* __restrict__ normal, size_t pix,
                                            float& nx, float& ny, float& nz) {
    const float* p = normal + pix * 3;
    float c0 = p[0], c1 = p[1], c2 = p[2];
    // channel-reversed, [0,1] -> [-1,1], L2 normalize
    float x = (c2 - 0.5f) * 2.0f;
    float y = (c1 - 0.5f) * 2.0f;
    float z = (c0 - 0.5f) * 2.0f;
    float d2 = x * x + y * y + z * z;
    float inv = d2 > 0.0f ? rsqrtf(d2) : 0.0f;
    nx = x * inv; ny = y * inv; nz = z * inv;
}

// 256 threads = 4 waves; wave g handles lights [g*120,(g+1)*120) for the SAME
// 64x4 pixels. 2048 blocks -> 8 blocks/CU -> 32 waves/CU (HW max).
__global__ __launch_bounds__(256) void k_fused(const float* __restrict__ normal,
                                               const float2* __restrict__ tab,
                                               float* __restrict__ out,
                                               unsigned* __restrict__ maxslot) {
    __shared__ float smem[NLS * 3 * 2];            // 11.25KB table; merge aliases it
    __shared__ float swmax[4];                     // per-wave partial max

    int tid = threadIdx.x;
    int bid = blockIdx.x;
    int bpb = HWPX / 256;                          // 1024 blocks per batch
    int b = bid / bpb;
    int g = tid >> 6;                              // wave-group = light quarter
    int li = tid & 63;                             // pixel lane
    int base_in_b = (bid % bpb) * 256 + li;

    // stage light table: 720 float4s, coalesced
    {
        const float4* gp = reinterpret_cast<const float4*>(tab + (size_t)b * NLS * 3);
        float4* sp4 = reinterpret_cast<float4*>(smem);
        sp4[tid]       = gp[tid];
        sp4[tid + 256] = gp[tid + 256];
        if (tid < 208) sp4[tid + 512] = gp[tid + 512];
    }

    // load 4 normals -> 2 packed pairs
    float nxs[PXPT], nys[PXPT], nzs[PXPT];
    #pragma unroll
    for (int k = 0; k < PXPT; ++k)
        load_normal(normal, (size_t)b * HWPX + base_in_b + k * 64,
                    nxs[k], nys[k], nzs[k]);
    f2 nx2[2], ny2[2], nz2[2];
    #pragma unroll
    for (int k = 0; k < 2; ++k) {
        nx2[k] = f2{nxs[2*k], nxs[2*k+1]};
        ny2[k] = f2{nys[2*k], nys[2*k+1]};
        nz2[k] = f2{nzs[2*k], nzs[2*k+1]};
    }

    // phi=0 light max seed (group 0 only): h=(0,r2,r2) -> s=(ny+nz)*r2
    float mx = 0.0f;
    if (g == 0) {
        #pragma unroll
        for (int k = 0; k < PXPT; ++k)
            mx = fmaxf(mx, (nys[k] + nzs[k]) * INV_SQRT2);
    }

    __syncthreads();

    f2 a0[2], a1[2], a2[2];
    #pragma unroll
    for (int k = 0; k < 2; ++k) { a0[k] = f2{0,0}; a1[k] = f2{0,0}; a2[k] = f2{0,0}; }

    const float2* Tg = reinterpret_cast<const float2*>(smem) + (size_t)g * (QNLS * 3);
    #pragma unroll 8
    for (int mm = 0; mm < QNLS; ++mm) {
        float2 q0 = Tg[mm * 3 + 0];                // {hx,hy}  (wave-uniform addr)
        float2 q1 = Tg[mm * 3 + 1];                // {hz,e0}
        float2 q2 = Tg[mm * 3 + 2];                // {e1,e2}
        f2 hx2 = {q0.x, q0.x}, hy2 = {q0.y, q0.y}, hz2 = {q1.x, q1.x};
        f2 e02 = {q1.y, q1.y}, e12 = {q2.x, q2.x}, e22 = {q2.y, q2.y};

        #pragma unroll
        for (int k = 0; k < 2; ++k) {
            f2 s = __builtin_elementwise_fma(nx2[k], hx2,
                   __builtin_elementwise_fma(ny2[k], hy2, nz2[k] * hz2));
            float sx = fmaxf(s.x, 0.0f);           // relu
            float sy = fmaxf(s.y, 0.0f);
            mx = fmaxf(mx, fmaxf(sx, sy));         // -> v_max3_f32
            f2 r = {sx, sy};
            f2 r2  = r * r;
            f2 r4  = r2 * r2;
            f2 r8  = r4 * r4;
            f2 r16 = r8 * r8;
            f2 r32 = r16 * r16;
            f2 r64 = r32 * r32;
            a0[k] = __builtin_elementwise_fma(r64, e02, a0[k]);
            a1[k] = __builtin_elementwise_fma(r64, e12, a1[k]);
            a2[k] = __builtin_elementwise_fma(r64, e22, a2[k]);
        }
    }

    // wave-64 max reduce
    #pragma unroll
    for (int off = 32; off > 0; off >>= 1)
        mx = fmaxf(mx, __shfl_xor(mx, off));
    if (li == 0) swmax[g] = mx;

    __syncthreads();   // all table reads done; smem now reusable as merge buffer

    // groups 1..3 deposit partials: stride 13 dwords (odd -> conflict-free)
    if (g > 0) {
        float* dst = smem + (size_t)(g - 1) * (64 * 13) + li * 13;
        dst[0]  = a0[0].x; dst[1]  = a0[0].y; dst[2]  = a0[1].x; dst[3]  = a0[1].y;
        dst[4]  = a1[0].x; dst[5]  = a1[0].y; dst[6]  = a1[1].x; dst[7]  = a1[1].y;
        dst[8]  = a2[0].x; dst[9]  = a2[0].y; dst[10] = a2[1].x; dst[11] = a2[1].y;
    }
    __syncthreads();

    if (tid == 0) {
        float bm = fmaxf(fmaxf(swmax[0], swmax[1]), fmaxf(swmax[2], swmax[3]));
        atomicMax(maxslot, __float_as_uint(bm));   // f32 >= 0: bit-monotone
    }

    if (g == 0) {
        #pragma unroll
        for (int gg = 0; gg < 3; ++gg) {
            const float* src = smem + (size_t)gg * (64 * 13) + li * 13;
            a0[0].x += src[0];  a0[0].y += src[1];  a0[1].x += src[2];  a0[1].y += src[3];
            a1[0].x += src[4];  a1[0].y += src[5];  a1[1].x += src[6];  a1[1].y += src[7];
            a2[0].x += src[8];  a2[0].y += src[9];  a2[1].x += src[10]; a2[1].y += src[11];
        }
        // unnormalized sums to out[b][c][h][w]; finalize scales by (1/max)^64
        float* ob = out + (size_t)b * 3 * HWPX;
        #pragma unroll
        for (int k = 0; k < PXPT; ++k) {
            int p = base_in_b + k * 64;
            f2 v0 = a0[k >> 1], v1 = a1[k >> 1], v2 = a2[k >> 1];
            int h = k & 1;
            ob[0 * HWPX + p] = v0[h];
            ob[1 * HWPX + p] = v1[h];
            ob[2 * HWPX + p] = v2[h];
        }
    }
}

__global__ __launch_bounds__(256) void k_finalize(float* __restrict__ out,
                                                  const unsigned* __restrict__ maxslot) {
    float im  = 1.0f / __uint_as_float(*maxslot);   // uniform scalar load
    float i2  = im * im;
    float i4  = i2 * i2;
    float i8  = i4 * i4;
    float i16 = i8 * i8;
    float i32 = i16 * i16;
    float scl = i32 * i32;                          // (1/max)^64
    int i = blockIdx.x * 256 + (int)threadIdx.x;    // over float4s
    float4* o = reinterpret_cast<float4*>(out);
    float4 v = o[i];
    v.x *= scl; v.y *= scl; v.z *= scl; v.w *= scl;
    o[i] = v;
}

extern "C" void kernel_launch(void* const* d_in, const int* in_sizes, int n_in,
                              void* d_out, int out_size, void* d_ws, size_t ws_size,
                              hipStream_t stream) {
    const float* env    = (const float*)d_in[0];   // (B,16,32,3) f32
    const float* normal = (const float*)d_in[1];   // (B,512,512,3) f32
    float* out = (float*)d_out;                    // (B,3,512,512) f32

    char* ws = (char*)d_ws;
    unsigned* maxslot = (unsigned*)ws;
    float2* tab = (float2*)(ws + 256);

    int nblocks = (NB * HWPX) / 256;               // 2048
    int fblocks = (NB * 3 * HWPX) / (4 * 256);     // 1536 (float4 granularity)

    hipLaunchKernelGGL(k_setup, dim3(1), dim3(NL), 0, stream, env, tab, maxslot);
    hipLaunchKernelGGL(k_fused, dim3(nblocks), dim3(256), 0, stream, normal, tab, out, maxslot);
    hipLaunchKernelGGL(k_finalize, dim3(fblocks), dim3(256), 0, stream, out, maxslot);
}

// Round 12
// 74.489 us; speedup vs baseline: 1.0619x; 1.0159x over previous
//
#include <hip/hip_runtime.h>

// Problem constants (match reference)
#define HWPX (512*512)      // pixels per batch
#define NB 2                // batches
#define NL 512              // EH*EW light directions (table rows)
#define NLS 480             // shadeable lights: phi=0 row (32 dirs) has coeff sin(0)=0
#define NPAIR 240           // light pairs
#define GPAIR 60            // pairs per wave-group (4 groups)
#define PXPT 4              // pixels per thread
constexpr float PI_F = 3.14159265358979323846f;
constexpr float INV_SQRT2 = 0.70710678118654752f;

typedef float f2 __attribute__((ext_vector_type(2)));

// ws layout (bytes):
//   [0]      unsigned max-bits slot (f32 >= 0, bit-monotone)
//   [256]    float tabq[2][240][12] : LIGHT-PAIRED table:
//            {hx0,hx1, hy0,hy1, hz0,hz1, e00,e01, e10,e11, e20,e21}
//            (e = env_channel * sin(phi)/60; phi=0 row excluded)
//
// Identities:
//  * (relu(s)/max)^64 == relu(s)^64 * (1/max)^64, |s|<=1 -> accumulate
//    UNNORMALIZED, track global max in-pass, finalize scales by (1/max)^64.
//  * phi=0 row: coeff==0 -> only matters for the max; h=(0,r2,r2) ->
//    s=(ny+nz)*r2 seeded analytically.
//
// R10 lesson: f2 pixel-pairing costs 6 splat v_movs per light-iteration
// (~10% of busy). LIGHT-pairing makes packed operands come straight from
// ds_read_b128; the only splats (pixel normals) are loop-invariant and
// hoisted. relu written as clamp so it can fold into the producing FMA.

__global__ void k_setup(const float* __restrict__ env,
                        float* __restrict__ tabq,
                        unsigned* __restrict__ maxslot) {
    int m = threadIdx.x;            // 512 threads, one per light dir
    if (m == 0) *maxslot = 0u;      // re-zeroed every launch (replay-safe)
    int p = m >> 5;                 // phi index (EH=16)
    int t = m & 31;                 // theta index (EW=32)
    if (p < 1) return;              // phi=0: zero coeff, handled analytically
    float phi = (float)p * (PI_F / 16.0f);
    float th  = (float)t * (2.0f * PI_F / 32.0f);
    float sp = sinf(phi), cp = cosf(phi);
    float st = sinf(th),  ct = cosf(th);
    // l = (st*sp, cp, -ct*sp); h = l + view(0,0,1), normalized
    float hx = st * sp;
    float hy = cp;
    float hz = 1.0f - ct * sp;
    float inv = rsqrtf(hx * hx + hy * hy + hz * hz);
    hx *= inv; hy *= inv; hz *= inv;
    float c = sp * (1.0f / 60.0f);  // solid-angle coeff and the /60 folded in
    int ms = m - 32;                // shadeable index 0..479
    int j = ms >> 1;                // pair index (pairs never straddle groups: 120 even)
    int slot = ms & 1;
    #pragma unroll
    for (int b = 0; b < NB; ++b) {
        const float* e = env + ((size_t)(b * NL + m)) * 3;
        float* dst = tabq + ((size_t)(b * NPAIR + j)) * 12 + slot;
        dst[0]  = hx;
        dst[2]  = hy;
        dst[4]  = hz;
        dst[6]  = e[0] * c;
        dst[8]  = e[1] * c;
        dst[10] = e[2] * c;
    }
}

__device__ __forceinline__ void load_normal(const float* __restrict__ normal, size_t pix,
                                            float& nx, float& ny, float& nz) {
    const float* p = normal + pix * 3;
    float c0 = p[0], c1 = p[1], c2 = p[2];
    // channel-reversed, [0,1] -> [-1,1], L2 normalize
    float x = (c2 - 0.5f) * 2.0f;
    float y = (c1 - 0.5f) * 2.0f;
    float z = (c0 - 0.5f) * 2.0f;
    float d2 = x * x + y * y + z * z;
    float inv = d2 > 0.0f ? rsqrtf(d2) : 0.0f;
    nx = x * inv; ny = y * inv; nz = z * inv;
}

// 256 threads = 4 waves; wave g handles light pairs [g*60,(g+1)*60) for the
// SAME 64x4 pixels. 2048 blocks.
__global__ __launch_bounds__(256) void k_fused(const float* __restrict__ normal,
                                               const float* __restrict__ tabq,
                                               float* __restrict__ out,
                                               unsigned* __restrict__ maxslot) {
    __shared__ float smem[NPAIR * 12];             // 11.25KB table; merge aliases it
    __shared__ float swmax[4];                     // per-wave partial max

    int tid = threadIdx.x;
    int bid = blockIdx.x;
    int bpb = HWPX / 256;                          // 1024 blocks per batch
    int b = bid / bpb;
    int g = tid >> 6;                              // wave-group = light quarter
    int li = tid & 63;                             // pixel lane
    int base_in_b = (bid % bpb) * 256 + li;

    // stage light table: 720 float4s, coalesced
    {
        const float4* gp = reinterpret_cast<const float4*>(tabq + (size_t)b * NPAIR * 12);
        float4* sp4 = reinterpret_cast<float4*>(smem);
        sp4[tid]       = gp[tid];
        sp4[tid + 256] = gp[tid + 256];
        if (tid < 208) sp4[tid + 512] = gp[tid + 512];
    }

    // load 4 normals; hoist f2 splats (loop-invariant)
    float nxs[PXPT], nys[PXPT], nzs[PXPT];
    #pragma unroll
    for (int k = 0; k < PXPT; ++k)
        load_normal(normal, (size_t)b * HWPX + base_in_b + k * 64,
                    nxs[k], nys[k], nzs[k]);
    f2 nx2[PXPT], ny2[PXPT], nz2[PXPT];
    #pragma unroll
    for (int k = 0; k < PXPT; ++k) {
        nx2[k] = f2{nxs[k], nxs[k]};
        ny2[k] = f2{nys[k], nys[k]};
        nz2[k] = f2{nzs[k], nzs[k]};
    }

    // phi=0 light max seed (group 0 only): h=(0,r2,r2) -> s=(ny+nz)*r2
    float mx = 0.0f;
    if (g == 0) {
        #pragma unroll
        for (int k = 0; k < PXPT; ++k)
            mx = fmaxf(mx, (nys[k] + nzs[k]) * INV_SQRT2);
    }

    __syncthreads();

    f2 a0[PXPT], a1[PXPT], a2[PXPT];               // per-px, per-light-slot partials
    #pragma unroll
    for (int k = 0; k < PXPT; ++k) { a0[k] = f2{0,0}; a1[k] = f2{0,0}; a2[k] = f2{0,0}; }

    const float4* Tg = reinterpret_cast<const float4*>(smem) + (size_t)g * (GPAIR * 3);
    #pragma unroll 4
    for (int j = 0; j < GPAIR; ++j) {
        float4 A = Tg[j * 3 + 0];                  // {hx0,hx1,hy0,hy1}
        float4 B = Tg[j * 3 + 1];                  // {hz0,hz1,e00,e01}
        float4 C = Tg[j * 3 + 2];                  // {e10,e11,e20,e21}
        f2 hx2 = {A.x, A.y}, hy2 = {A.z, A.w}, hz2 = {B.x, B.y};
        f2 e02 = {B.z, B.w}, e12 = {C.x, C.y}, e22 = {C.z, C.w};

        #pragma unroll
        for (int k = 0; k < PXPT; ++k) {
            f2 s = __builtin_elementwise_fma(nx2[k], hx2,
                   __builtin_elementwise_fma(ny2[k], hy2, nz2[k] * hz2));
            // relu as clamp (|s|<=1): foldable into the producing FMA's clamp bit
            float sx = fminf(fmaxf(s.x, 0.0f), 1.0f);
            float sy = fminf(fmaxf(s.y, 0.0f), 1.0f);
            mx = fmaxf(mx, fmaxf(sx, sy));         // -> v_max3_f32
            f2 r = {sx, sy};
            f2 r2  = r * r;
            f2 r4  = r2 * r2;
            f2 r8  = r4 * r4;
            f2 r16 = r8 * r8;
            f2 r32 = r16 * r16;
            f2 r64 = r32 * r32;
            a0[k] = __builtin_elementwise_fma(r64, e02, a0[k]);
            a1[k] = __builtin_elementwise_fma(r64, e12, a1[k]);
            a2[k] = __builtin_elementwise_fma(r64, e22, a2[k]);
        }
    }

    // collapse light-slot halves
    float b0[PXPT], b1[PXPT], b2[PXPT];
    #pragma unroll
    for (int k = 0; k < PXPT; ++k) {
        b0[k] = a0[k].x + a0[k].y;
        b1[k] = a1[k].x + a1[k].y;
        b2[k] = a2[k].x + a2[k].y;
    }

    // wave-64 max reduce
    #pragma unroll
    for (int off = 32; off > 0; off >>= 1)
        mx = fmaxf(mx, __shfl_xor(mx, off));
    if (li == 0) swmax[g] = mx;

    __syncthreads();   // all table reads done; smem now reusable as merge buffer

    // groups 1..3 deposit partials: stride 13 dwords (odd -> conflict-free)
    if (g > 0) {
        float* dst = smem + (size_t)(g - 1) * (64 * 13) + li * 13;
        #pragma unroll
        for (int k = 0; k < PXPT; ++k) {
            dst[k]     = b0[k];
            dst[k + 4] = b1[k];
            dst[k + 8] = b2[k];
        }
    }
    __syncthreads();

    if (tid == 0) {
        float bm = fmaxf(fmaxf(swmax[0], swmax[1]), fmaxf(swmax[2], swmax[3]));
        atomicMax(maxslot, __float_as_uint(bm));   // f32 >= 0: bit-monotone
    }

    if (g == 0) {
        #pragma unroll
        for (int gg = 0; gg < 3; ++gg) {
            const float* src = smem + (size_t)gg * (64 * 13) + li * 13;
            #pragma unroll
            for (int k = 0; k < PXPT; ++k) {
                b0[k] += src[k];
                b1[k] += src[k + 4];
                b2[k] += src[k + 8];
            }
        }
        // unnormalized sums to out[b][c][h][w]; finalize scales by (1/max)^64
        float* ob = out + (size_t)b * 3 * HWPX;
        #pragma unroll
        for (int k = 0; k < PXPT; ++k) {
            int p = base_in_b + k * 64;
            ob[0 * HWPX + p] = b0[k];
            ob[1 * HWPX + p] = b1[k];
            ob[2 * HWPX + p] = b2[k];
        }
    }
}

__global__ __launch_bounds__(256) void k_finalize(float* __restrict__ out,
                                                  const unsigned* __restrict__ maxslot) {
    float im  = 1.0f / __uint_as_float(*maxslot);   // uniform scalar load
    float i2  = im * im;
    float i4  = i2 * i2;
    float i8  = i4 * i4;
    float i16 = i8 * i8;
    float i32 = i16 * i16;
    float scl = i32 * i32;                          // (1/max)^64
    int i = blockIdx.x * 256 + (int)threadIdx.x;    // over float4s
    float4* o = reinterpret_cast<float4*>(out);
    float4 v = o[i];
    v.x *= scl; v.y *= scl; v.z *= scl; v.w *= scl;
    o[i] = v;
}

extern "C" void kernel_launch(void* const* d_in, const int* in_sizes, int n_in,
                              void* d_out, int out_size, void* d_ws, size_t ws_size,
                              hipStream_t stream) {
    const float* env    = (const float*)d_in[0];   // (B,16,32,3) f32
    const float* normal = (const float*)d_in[1];   // (B,512,512,3) f32
    float* out = (float*)d_out;                    // (B,3,512,512) f32

    char* ws = (char*)d_ws;
    unsigned* maxslot = (unsigned*)ws;
    float* tabq = (float*)(ws + 256);

    int nblocks = (NB * HWPX) / 256;               // 2048
    int fblocks = (NB * 3 * HWPX) / (4 * 256);     // 1536 (float4 granularity)

    hipLaunchKernelGGL(k_setup, dim3(1), dim3(NL), 0, stream, env, tabq, maxslot);
    hipLaunchKernelGGL(k_fused, dim3(nblocks), dim3(256), 0, stream, normal, tabq, out, maxslot);
    hipLaunchKernelGGL(k_finalize, dim3(fblocks), dim3(256), 0, stream, out, maxslot);
}